// Round 1
// baseline (569.612 us; speedup 1.0000x reference)
//
#include <hip/hip_runtime.h>

#define D 32          // MOTIF_DIM
#define H 64          // HIDDEN

// ---------------------------------------------------------------------------
// Kernel 1: per-node precompute  P = X @ W1[0:32,:],  Q = X @ W1[32:64,:]
// One wave (64 lanes) handles one node: lane j computes P[n][j], Q[n][j].
// x-row reads are wave-uniform (scalar loads); W1 reads are coalesced.
// ---------------------------------------------------------------------------
__global__ __launch_bounds__(256) void node_pq(
    const float* __restrict__ x, const float* __restrict__ W1,
    float* __restrict__ P, float* __restrict__ Q, int n_nodes) {
  int tid = blockIdx.x * 256 + threadIdx.x;
  int node = tid >> 6;
  if (node >= n_nodes) return;
  int j = tid & 63;
  const float* xr = x + (size_t)node * D;
  float ap = 0.f, aq = 0.f;
#pragma unroll
  for (int k = 0; k < D; ++k) {
    float xv = xr[k];                       // wave-uniform -> s_load
    ap = fmaf(xv, W1[k * H + j], ap);
    aq = fmaf(xv, W1[(D + k) * H + j], aq);
  }
  P[(size_t)node * H + j] = ap;
  Q[(size_t)node * H + j] = aq;
}

// ---------------------------------------------------------------------------
// Kernel 2: one thread per edge.
//   h = relu(P[s] + Q[d] + |mu-mv|@W1c + (mu*mv)@W1d + b1);  g = sigmoid(h@W2+b2)
// W1c/W1d/b1/W2 addresses are wave-uniform -> scalar loads, v_fmac v,s,v.
// ---------------------------------------------------------------------------
__global__ __launch_bounds__(256) void edge_gate(
    const float* __restrict__ x, const int* __restrict__ ei,
    const float* __restrict__ W1, const float* __restrict__ b1,
    const float* __restrict__ W2, const float* __restrict__ b2,
    const float* __restrict__ P, const float* __restrict__ Q,
    float* __restrict__ out, int nE) {
  int e = blockIdx.x * 256 + threadIdx.x;
  if (e >= nE) return;
  int s = ei[e];
  int d = ei[e + nE];

  const float4* mu4 = (const float4*)(x + (size_t)s * D);
  const float4* mv4 = (const float4*)(x + (size_t)d * D);
  float c[D], p[D];
#pragma unroll
  for (int q = 0; q < D / 4; ++q) {
    float4 a = mu4[q];
    float4 b = mv4[q];
    c[4*q+0] = fabsf(a.x - b.x); p[4*q+0] = a.x * b.x;
    c[4*q+1] = fabsf(a.y - b.y); p[4*q+1] = a.y * b.y;
    c[4*q+2] = fabsf(a.z - b.z); p[4*q+2] = a.z * b.z;
    c[4*q+3] = fabsf(a.w - b.w); p[4*q+3] = a.w * b.w;
  }

  const float4* Pr = (const float4*)(P + (size_t)s * H);
  const float4* Qr = (const float4*)(Q + (size_t)d * H);
  const float* Wc = W1 + 2 * D * H;   // rows 64..95  (|mu-mv| block)
  const float* Wd = W1 + 3 * D * H;   // rows 96..127 (mu*mv block)

  float z = b2[0];
#pragma unroll 2
  for (int jc = 0; jc < H / 4; ++jc) {
    float4 pv = Pr[jc];
    float4 qv = Qr[jc];
    float a0 = pv.x + qv.x + b1[4*jc+0];
    float a1 = pv.y + qv.y + b1[4*jc+1];
    float a2 = pv.z + qv.z + b1[4*jc+2];
    float a3 = pv.w + qv.w + b1[4*jc+3];
#pragma unroll
    for (int k = 0; k < D; ++k) {
      const float* wcr = Wc + k * H + 4 * jc;   // uniform -> s_load_dwordx4
      const float* wdr = Wd + k * H + 4 * jc;
      a0 = fmaf(c[k], wcr[0], a0); a0 = fmaf(p[k], wdr[0], a0);
      a1 = fmaf(c[k], wcr[1], a1); a1 = fmaf(p[k], wdr[1], a1);
      a2 = fmaf(c[k], wcr[2], a2); a2 = fmaf(p[k], wdr[2], a2);
      a3 = fmaf(c[k], wcr[3], a3); a3 = fmaf(p[k], wdr[3], a3);
    }
    a0 = fmaxf(a0, 0.f); a1 = fmaxf(a1, 0.f);
    a2 = fmaxf(a2, 0.f); a3 = fmaxf(a3, 0.f);
    z = fmaf(a0, W2[4*jc+0], z);
    z = fmaf(a1, W2[4*jc+1], z);
    z = fmaf(a2, W2[4*jc+2], z);
    z = fmaf(a3, W2[4*jc+3], z);
  }

  float g = 1.f / (1.f + __expf(-z));
  g = fminf(fmaxf(g, 0.f), 1.f);
  out[e] = g;
}

// ---------------------------------------------------------------------------
// Fallback (if ws too small): compute all four W1 blocks per edge.
// ---------------------------------------------------------------------------
__global__ __launch_bounds__(256) void edge_full(
    const float* __restrict__ x, const int* __restrict__ ei,
    const float* __restrict__ W1, const float* __restrict__ b1,
    const float* __restrict__ W2, const float* __restrict__ b2,
    float* __restrict__ out, int nE) {
  int e = blockIdx.x * 256 + threadIdx.x;
  if (e >= nE) return;
  int s = ei[e];
  int d = ei[e + nE];
  const float4* mu4 = (const float4*)(x + (size_t)s * D);
  const float4* mv4 = (const float4*)(x + (size_t)d * D);
  float mu[D], mv[D], c[D], p[D];
#pragma unroll
  for (int q = 0; q < D / 4; ++q) {
    float4 a = mu4[q];
    float4 b = mv4[q];
    mu[4*q+0] = a.x; mv[4*q+0] = b.x; c[4*q+0] = fabsf(a.x-b.x); p[4*q+0] = a.x*b.x;
    mu[4*q+1] = a.y; mv[4*q+1] = b.y; c[4*q+1] = fabsf(a.y-b.y); p[4*q+1] = a.y*b.y;
    mu[4*q+2] = a.z; mv[4*q+2] = b.z; c[4*q+2] = fabsf(a.z-b.z); p[4*q+2] = a.z*b.z;
    mu[4*q+3] = a.w; mv[4*q+3] = b.w; c[4*q+3] = fabsf(a.w-b.w); p[4*q+3] = a.w*b.w;
  }
  float z = b2[0];
  for (int j = 0; j < H; ++j) {
    float a = b1[j];
#pragma unroll
    for (int k = 0; k < D; ++k) {
      a = fmaf(mu[k], W1[k * H + j], a);
      a = fmaf(mv[k], W1[(D + k) * H + j], a);
      a = fmaf(c[k],  W1[(2 * D + k) * H + j], a);
      a = fmaf(p[k],  W1[(3 * D + k) * H + j], a);
    }
    a = fmaxf(a, 0.f);
    z = fmaf(a, W2[j], z);
  }
  float g = 1.f / (1.f + __expf(-z));
  g = fminf(fmaxf(g, 0.f), 1.f);
  out[e] = g;
}

extern "C" void kernel_launch(void* const* d_in, const int* in_sizes, int n_in,
                              void* d_out, int out_size, void* d_ws, size_t ws_size,
                              hipStream_t stream) {
  const float* x  = (const float*)d_in[0];
  const int*   ei = (const int*)d_in[1];
  const float* W1 = (const float*)d_in[2];
  const float* b1 = (const float*)d_in[3];
  const float* W2 = (const float*)d_in[4];
  const float* b2 = (const float*)d_in[5];
  float* out = (float*)d_out;

  int nN = in_sizes[0] / D;      // 100000
  int nE = in_sizes[1] / 2;      // 1600000

  size_t need = (size_t)nN * H * 2 * sizeof(float);
  if (ws_size >= need) {
    float* P = (float*)d_ws;
    float* Q = P + (size_t)nN * H;
    node_pq<<<(nN * 64 + 255) / 256, 256, 0, stream>>>(x, W1, P, Q, nN);
    edge_gate<<<(nE + 255) / 256, 256, 0, stream>>>(x, ei, W1, b1, W2, b2, P, Q, out, nE);
  } else {
    edge_full<<<(nE + 255) / 256, 256, 0, stream>>>(x, ei, W1, b1, W2, b2, out, nE);
  }
}

// Round 2
// 568.009 us; speedup vs baseline: 1.0028x; 1.0028x over previous
//
#include <hip/hip_runtime.h>

#define D 32          // MOTIF_DIM
#define H 64          // HIDDEN
// Per-node record, bf16: [ P (64 vals, 128B) | x (32 vals, 64B) | Q (64 vals, 128B) ]
// = 320 B, 64B-aligned for every node (320 = 5*64).
// src edge endpoint reads bytes   0..191 (P + x)  — contiguous
// dst edge endpoint reads bytes 128..319 (x + Q)  — contiguous
#define REC_U16  160
#define REC_U32  80

__device__ __forceinline__ unsigned short f2bf(float f) {   // round-to-nearest-even
  unsigned u = __float_as_uint(f);
  u += 0x7fffu + ((u >> 16) & 1u);
  return (unsigned short)(u >> 16);
}
__device__ __forceinline__ float bf_lo(unsigned u) { return __uint_as_float(u << 16); }
__device__ __forceinline__ float bf_hi(unsigned u) { return __uint_as_float(u & 0xffff0000u); }

// ---------------------------------------------------------------------------
// Kernel 1: per-node P = X@W1[0:32,:], Q = X@W1[32:64,:]; pack [P|x|Q] bf16.
// One wave per node; lane j handles column j.
// ---------------------------------------------------------------------------
__global__ __launch_bounds__(256) void node_pack(
    const float* __restrict__ x, const float* __restrict__ W1,
    unsigned short* __restrict__ rec, int n_nodes) {
  int tid = blockIdx.x * 256 + threadIdx.x;
  int node = tid >> 6;
  if (node >= n_nodes) return;
  int j = tid & 63;
  const float* xr = x + (size_t)node * D;
  float ap = 0.f, aq = 0.f;
#pragma unroll
  for (int k = 0; k < D; ++k) {
    float xv = xr[k];                      // wave-uniform row -> L1 broadcast
    ap = fmaf(xv, W1[k * H + j], ap);
    aq = fmaf(xv, W1[(D + k) * H + j], aq);
  }
  unsigned short* r = rec + (size_t)node * REC_U16;
  r[j]      = f2bf(ap);                    // P
  r[96 + j] = f2bf(aq);                    // Q
  if (j < D) r[64 + j] = f2bf(xr[j]);      // x
}

// ---------------------------------------------------------------------------
// Kernel 2: one thread per edge, gathers two contiguous 192B bf16 chunks.
// ---------------------------------------------------------------------------
__global__ __launch_bounds__(256) void edge_gate_bf(
    const unsigned int* __restrict__ rec, const int* __restrict__ ei,
    const float* __restrict__ W1, const float* __restrict__ b1,
    const float* __restrict__ W2, const float* __restrict__ b2,
    float* __restrict__ out, int nE) {
  int e = blockIdx.x * 256 + threadIdx.x;
  if (e >= nE) return;
  int s = ei[e];
  int d = ei[e + nE];

  const unsigned int* rs = rec + (size_t)s * REC_U32;       // P@0, x@32 (dwords)
  const unsigned int* rd = rec + (size_t)d * REC_U32;       // x@32, Q@48

  // ---- unpack x rows -> c = |mu-mv|, p = mu*mv ----
  float c[D], p[D];
  const uint4* xs = (const uint4*)(rs + 32);
  const uint4* xd = (const uint4*)(rd + 32);
#pragma unroll
  for (int q = 0; q < 4; ++q) {
    uint4 a = xs[q];
    uint4 b = xd[q];
    unsigned au[4] = {a.x, a.y, a.z, a.w};
    unsigned bu[4] = {b.x, b.y, b.z, b.w};
#pragma unroll
    for (int t = 0; t < 4; ++t) {
      float m0 = bf_lo(au[t]), m1 = bf_hi(au[t]);
      float n0 = bf_lo(bu[t]), n1 = bf_hi(bu[t]);
      int i = q * 8 + t * 2;
      c[i]     = fabsf(m0 - n0); p[i]     = m0 * n0;
      c[i + 1] = fabsf(m1 - n1); p[i + 1] = m1 * n1;
    }
  }

  const float* Wc = W1 + 2 * D * H;   // |mu-mv| block
  const float* Wd = W1 + 3 * D * H;   // mu*mv  block
  float z = b2[0];

  for (int jb = 0; jb < 8; ++jb) {    // 8 hidden units per iteration
    uint4 pv = *(const uint4*)(rs + jb * 4);        // P[8jb..8jb+7]
    uint4 qv = *(const uint4*)(rd + 48 + jb * 4);   // Q[8jb..8jb+7]
    float acc[8];
    acc[0] = bf_lo(pv.x) + bf_lo(qv.x) + b1[8 * jb + 0];
    acc[1] = bf_hi(pv.x) + bf_hi(qv.x) + b1[8 * jb + 1];
    acc[2] = bf_lo(pv.y) + bf_lo(qv.y) + b1[8 * jb + 2];
    acc[3] = bf_hi(pv.y) + bf_hi(qv.y) + b1[8 * jb + 3];
    acc[4] = bf_lo(pv.z) + bf_lo(qv.z) + b1[8 * jb + 4];
    acc[5] = bf_hi(pv.z) + bf_hi(qv.z) + b1[8 * jb + 5];
    acc[6] = bf_lo(pv.w) + bf_lo(qv.w) + b1[8 * jb + 6];
    acc[7] = bf_hi(pv.w) + bf_hi(qv.w) + b1[8 * jb + 7];
#pragma unroll
    for (int k = 0; k < D; ++k) {
      const float* wcr = Wc + k * H + 8 * jb;   // wave-uniform -> scalar loads
      const float* wdr = Wd + k * H + 8 * jb;
#pragma unroll
      for (int t = 0; t < 8; ++t) {
        acc[t] = fmaf(c[k], wcr[t], acc[t]);
        acc[t] = fmaf(p[k], wdr[t], acc[t]);
      }
    }
#pragma unroll
    for (int t = 0; t < 8; ++t)
      z = fmaf(fmaxf(acc[t], 0.f), W2[8 * jb + t], z);
  }

  float g = 1.f / (1.f + __expf(-z));
  g = fminf(fmaxf(g, 0.f), 1.f);
  out[e] = g;
}

// ---------------------------------------------------------------------------
// Fallback (ws too small): all-fp32, all four blocks per edge.
// ---------------------------------------------------------------------------
__global__ __launch_bounds__(256) void edge_full(
    const float* __restrict__ x, const int* __restrict__ ei,
    const float* __restrict__ W1, const float* __restrict__ b1,
    const float* __restrict__ W2, const float* __restrict__ b2,
    float* __restrict__ out, int nE) {
  int e = blockIdx.x * 256 + threadIdx.x;
  if (e >= nE) return;
  int s = ei[e];
  int d = ei[e + nE];
  const float4* mu4 = (const float4*)(x + (size_t)s * D);
  const float4* mv4 = (const float4*)(x + (size_t)d * D);
  float mu[D], mv[D], c[D], p[D];
#pragma unroll
  for (int q = 0; q < D / 4; ++q) {
    float4 a = mu4[q];
    float4 b = mv4[q];
    mu[4*q+0] = a.x; mv[4*q+0] = b.x; c[4*q+0] = fabsf(a.x-b.x); p[4*q+0] = a.x*b.x;
    mu[4*q+1] = a.y; mv[4*q+1] = b.y; c[4*q+1] = fabsf(a.y-b.y); p[4*q+1] = a.y*b.y;
    mu[4*q+2] = a.z; mv[4*q+2] = b.z; c[4*q+2] = fabsf(a.z-b.z); p[4*q+2] = a.z*b.z;
    mu[4*q+3] = a.w; mv[4*q+3] = b.w; c[4*q+3] = fabsf(a.w-b.w); p[4*q+3] = a.w*b.w;
  }
  float z = b2[0];
  for (int j = 0; j < H; ++j) {
    float a = b1[j];
#pragma unroll
    for (int k = 0; k < D; ++k) {
      a = fmaf(mu[k], W1[k * H + j], a);
      a = fmaf(mv[k], W1[(D + k) * H + j], a);
      a = fmaf(c[k],  W1[(2 * D + k) * H + j], a);
      a = fmaf(p[k],  W1[(3 * D + k) * H + j], a);
    }
    a = fmaxf(a, 0.f);
    z = fmaf(a, W2[j], z);
  }
  float g = 1.f / (1.f + __expf(-z));
  g = fminf(fmaxf(g, 0.f), 1.f);
  out[e] = g;
}

extern "C" void kernel_launch(void* const* d_in, const int* in_sizes, int n_in,
                              void* d_out, int out_size, void* d_ws, size_t ws_size,
                              hipStream_t stream) {
  const float* x  = (const float*)d_in[0];
  const int*   ei = (const int*)d_in[1];
  const float* W1 = (const float*)d_in[2];
  const float* b1 = (const float*)d_in[3];
  const float* W2 = (const float*)d_in[4];
  const float* b2 = (const float*)d_in[5];
  float* out = (float*)d_out;

  int nN = in_sizes[0] / D;      // 100000
  int nE = in_sizes[1] / 2;      // 1600000

  size_t need = (size_t)nN * REC_U16 * sizeof(unsigned short);  // 32 MB
  if (ws_size >= need) {
    unsigned short* rec = (unsigned short*)d_ws;
    node_pack<<<(nN * 64 + 255) / 256, 256, 0, stream>>>(x, W1, rec, nN);
    edge_gate_bf<<<(nE + 255) / 256, 256, 0, stream>>>(
        (const unsigned int*)rec, ei, W1, b1, W2, b2, out, nE);
  } else {
    edge_full<<<(nE + 255) / 256, 256, 0, stream>>>(x, ei, W1, b1, W2, b2, out, nE);
  }
}

// Round 3
// 132.024 us; speedup vs baseline: 4.3144x; 4.3023x over previous
//
#include <hip/hip_runtime.h>

#define D 32          // MOTIF_DIM
#define H 64          // HIDDEN

typedef __attribute__((ext_vector_type(8))) short bf16x8;
typedef __attribute__((ext_vector_type(4))) float f32x4;

__device__ __forceinline__ short f2bf_s(float f) {   // round-to-nearest-even
  unsigned u = __float_as_uint(f);
  u += 0x7fffu + ((u >> 16) & 1u);
  return (short)(u >> 16);
}
__device__ __forceinline__ float bf2f(short s) {
  return __uint_as_float(((unsigned)(unsigned short)s) << 16);
}

// ---------------------------------------------------------------------------
// Pack x (fp32) -> bf16 rows. 64 B per node row, one 64B granule per gather.
// ---------------------------------------------------------------------------
__global__ __launch_bounds__(256) void pack_x(
    const float* __restrict__ x, short* __restrict__ xbf, int n4) {
  int t = blockIdx.x * 256 + threadIdx.x;
  if (t >= n4) return;
  float4 v = ((const float4*)x)[t];
  short4 o;
  o.x = f2bf_s(v.x); o.y = f2bf_s(v.y); o.z = f2bf_s(v.z); o.w = f2bf_s(v.w);
  ((short4*)xbf)[t] = o;
}

// ---------------------------------------------------------------------------
// Build B-fragment table: frag f = t*4+s (t = N-tile 0..3, s = K-step 0..3).
// Lane l element j holds B[k = s*32 + (l>>4)*8 + j][n = t*16 + (l&15)]
// from W1 [128][64] row-major fp32, converted to bf16.
// Table: btab[(f*64 + l)*8 + j], 8192 shorts = 16 KB.
// ---------------------------------------------------------------------------
__global__ __launch_bounds__(256) void build_btab(
    const float* __restrict__ W1, short* __restrict__ btab) {
  int id = blockIdx.x * 256 + threadIdx.x;      // 0..8191
  if (id >= 16 * 64 * 8) return;
  int j = id & 7;
  int l = (id >> 3) & 63;
  int f = id >> 9;
  int s = f & 3, t = f >> 2;
  int k = s * 32 + (l >> 4) * 8 + j;
  int n = t * 16 + (l & 15);
  btab[id] = f2bf_s(W1[k * H + n]);
}

// ---------------------------------------------------------------------------
// Main: one wave per 16-edge tile (grid-stride). Per tile:
//   2 gathered 16B bf16 loads/lane (mu,mv A-frags direct from memory),
//   c,p A-frags computed in-lane, 16 MFMA 16x16x32_bf16, fused layer2.
// No LDS, no __syncthreads.
// ---------------------------------------------------------------------------
__global__ __launch_bounds__(256) void edge_mfma(
    const short* __restrict__ xbf, const short* __restrict__ btab,
    const int* __restrict__ ei,
    const float* __restrict__ b1, const float* __restrict__ W2,
    const float* __restrict__ b2, float* __restrict__ out,
    int nE, int nTiles) {
  int lane = threadIdx.x & 63;
  int wid  = (blockIdx.x * 256 + threadIdx.x) >> 6;
  int nW   = (gridDim.x * 256) >> 6;
  int m = lane & 15;        // A-row (edge within tile) / C-col (hidden within tile)
  int q = lane >> 4;        // quad

  bf16x8 B[16];
#pragma unroll
  for (int f = 0; f < 16; ++f)
    B[f] = *(const bf16x8*)(btab + (f * 64 + lane) * 8);

  float b1v[4], w2v[4];
#pragma unroll
  for (int t = 0; t < 4; ++t) { b1v[t] = b1[t * 16 + m]; w2v[t] = W2[t * 16 + m]; }
  float bias2 = b2[0];

  for (int tile = wid; tile < nTiles; tile += nW) {
    int e  = tile * 16 + m;
    int ec = e < nE ? e : nE - 1;
    int s  = ei[ec];
    int dd = ei[ec + nE];

    bf16x8 amu = *(const bf16x8*)(xbf + s  * D + q * 8);
    bf16x8 amv = *(const bf16x8*)(xbf + dd * D + q * 8);
    bf16x8 ac, ap;
#pragma unroll
    for (int j = 0; j < 8; ++j) {
      float a = bf2f(amu[j]), b = bf2f(amv[j]);
      ac[j] = f2bf_s(fabsf(a - b));
      ap[j] = f2bf_s(a * b);
    }

    float part[4] = {0.f, 0.f, 0.f, 0.f};
#pragma unroll
    for (int t = 0; t < 4; ++t) {
      f32x4 acc = {0.f, 0.f, 0.f, 0.f};
      acc = __builtin_amdgcn_mfma_f32_16x16x32_bf16(amu, B[t * 4 + 0], acc, 0, 0, 0);
      acc = __builtin_amdgcn_mfma_f32_16x16x32_bf16(amv, B[t * 4 + 1], acc, 0, 0, 0);
      acc = __builtin_amdgcn_mfma_f32_16x16x32_bf16(ac,  B[t * 4 + 2], acc, 0, 0, 0);
      acc = __builtin_amdgcn_mfma_f32_16x16x32_bf16(ap,  B[t * 4 + 3], acc, 0, 0, 0);
      // lane holds h[edge = q*4+r][hidden = t*16+m]
#pragma unroll
      for (int r = 0; r < 4; ++r) {
        float h = acc[r] + b1v[t];
        part[r] = fmaf(fmaxf(h, 0.f), w2v[t], part[r]);
      }
    }
    // reduce over the 16 lanes of each quad (sum over hidden dim)
#pragma unroll
    for (int mask = 1; mask < 16; mask <<= 1)
#pragma unroll
      for (int r = 0; r < 4; ++r)
        part[r] += __shfl_xor(part[r], mask, 64);

    if (m < 4) {
      int ew = tile * 16 + q * 4 + m;     // edge for r = m
      if (ew < nE) {
        float z = part[m] + bias2;
        float g = 1.f / (1.f + __expf(-z));
        out[ew] = fminf(fmaxf(g, 0.f), 1.f);
      }
    }
  }
}

// ---------------------------------------------------------------------------
// Fallback (ws too small): all-fp32 per edge, no workspace needed.
// ---------------------------------------------------------------------------
__global__ __launch_bounds__(256) void edge_full(
    const float* __restrict__ x, const int* __restrict__ ei,
    const float* __restrict__ W1, const float* __restrict__ b1,
    const float* __restrict__ W2, const float* __restrict__ b2,
    float* __restrict__ out, int nE) {
  int e = blockIdx.x * 256 + threadIdx.x;
  if (e >= nE) return;
  int s = ei[e];
  int d = ei[e + nE];
  const float4* mu4 = (const float4*)(x + (size_t)s * D);
  const float4* mv4 = (const float4*)(x + (size_t)d * D);
  float mu[D], mv[D], c[D], p[D];
#pragma unroll
  for (int qq = 0; qq < D / 4; ++qq) {
    float4 a = mu4[qq];
    float4 b = mv4[qq];
    mu[4*qq+0] = a.x; mv[4*qq+0] = b.x; c[4*qq+0] = fabsf(a.x-b.x); p[4*qq+0] = a.x*b.x;
    mu[4*qq+1] = a.y; mv[4*qq+1] = b.y; c[4*qq+1] = fabsf(a.y-b.y); p[4*qq+1] = a.y*b.y;
    mu[4*qq+2] = a.z; mv[4*qq+2] = b.z; c[4*qq+2] = fabsf(a.z-b.z); p[4*qq+2] = a.z*b.z;
    mu[4*qq+3] = a.w; mv[4*qq+3] = b.w; c[4*qq+3] = fabsf(a.w-b.w); p[4*qq+3] = a.w*b.w;
  }
  float z = b2[0];
  for (int j = 0; j < H; ++j) {
    float a = b1[j];
#pragma unroll
    for (int k = 0; k < D; ++k) {
      a = fmaf(mu[k], W1[k * H + j], a);
      a = fmaf(mv[k], W1[(D + k) * H + j], a);
      a = fmaf(c[k],  W1[(2 * D + k) * H + j], a);
      a = fmaf(p[k],  W1[(3 * D + k) * H + j], a);
    }
    a = fmaxf(a, 0.f);
    z = fmaf(a, W2[j], z);
  }
  float g = 1.f / (1.f + __expf(-z));
  out[e] = fminf(fmaxf(g, 0.f), 1.f);
}

extern "C" void kernel_launch(void* const* d_in, const int* in_sizes, int n_in,
                              void* d_out, int out_size, void* d_ws, size_t ws_size,
                              hipStream_t stream) {
  const float* x  = (const float*)d_in[0];
  const int*   ei = (const int*)d_in[1];
  const float* W1 = (const float*)d_in[2];
  const float* b1 = (const float*)d_in[3];
  const float* W2 = (const float*)d_in[4];
  const float* b2 = (const float*)d_in[5];
  float* out = (float*)d_out;

  int nN = in_sizes[0] / D;      // 100000
  int nE = in_sizes[1] / 2;      // 1600000

  size_t xbf_shorts = (size_t)nN * D;                 // 6.4 MB
  size_t need = (xbf_shorts + 16 * 64 * 8) * sizeof(short);
  if (ws_size >= need) {
    short* xbf  = (short*)d_ws;
    short* btab = xbf + xbf_shorts;
    int n4 = nN * D / 4;
    pack_x<<<(n4 + 255) / 256, 256, 0, stream>>>(x, xbf, n4);
    build_btab<<<(16 * 64 * 8 + 255) / 256, 256, 0, stream>>>(W1, btab);
    int nTiles = (nE + 15) / 16;
    edge_mfma<<<2048, 256, 0, stream>>>(xbf, btab, ei, b1, W2, b2, out, nE, nTiles);
  } else {
    edge_full<<<(nE + 255) / 256, 256, 0, stream>>>(x, ei, W1, b1, W2, b2, out, nE);
  }
}

// Round 4
// 130.135 us; speedup vs baseline: 4.3771x; 1.0145x over previous
//
#include <hip/hip_runtime.h>

#define D 32          // MOTIF_DIM
#define H 64          // HIDDEN

typedef __attribute__((ext_vector_type(8))) short bf16x8;
typedef __attribute__((ext_vector_type(4))) float f32x4;

union AB { uint4 u; bf16x8 v; };

__device__ __forceinline__ short f2bf_s(float f) {   // round-to-nearest-even
  unsigned u = __float_as_uint(f);
  u += 0x7fffu + ((u >> 16) & 1u);
  return (short)(u >> 16);
}

// pack two f32 (lo,hi) into one dword of bf16 [lo | hi<<16], round-to-zero.
__device__ __forceinline__ unsigned pack_bf2(float lo, float hi) {
  return __builtin_amdgcn_perm(__float_as_uint(hi), __float_as_uint(lo), 0x07060302u);
}

// ---------------------------------------------------------------------------
// Fused prep: blocks [0, nPack) convert x fp32 -> bf16 rows (RNE);
// blocks [nPack, nPack+32) build the W1 B-fragment table (16 frags x 64 lanes
// x 8 bf16 = 16 KB). Frag f = t*4+s: lane l elem j = W1[s*32+(l>>4)*8+j][t*16+(l&15)].
// ---------------------------------------------------------------------------
__global__ __launch_bounds__(256) void prep(
    const float* __restrict__ x, const float* __restrict__ W1,
    short* __restrict__ xbf, short* __restrict__ btab, int n4, int nPack) {
  int b = blockIdx.x;
  if (b < nPack) {
    int i = b * 256 + threadIdx.x;
    if (i < n4) {
      float4 v = ((const float4*)x)[i];
      short4 o;
      o.x = f2bf_s(v.x); o.y = f2bf_s(v.y); o.z = f2bf_s(v.z); o.w = f2bf_s(v.w);
      ((short4*)xbf)[i] = o;
    }
  } else {
    int id = (b - nPack) * 256 + threadIdx.x;      // 0..8191
    if (id < 16 * 64 * 8) {
      int j = id & 7;
      int l = (id >> 3) & 63;
      int f = id >> 9;
      int s = f & 3, t = f >> 2;
      int k = s * 32 + (l >> 4) * 8 + j;
      int n = t * 16 + (l & 15);
      btab[id] = f2bf_s(W1[k * H + n]);
    }
  }
}

// ---------------------------------------------------------------------------
// Main: one wave per 16-edge tile (grid-stride), software-pipelined gathers.
// Per tile: 2 gathered 16B bf16 loads/lane (A-frags direct from memory),
// c,p frags computed in-lane (dword math + v_perm pack), 16 MFMA, fused L2.
// ---------------------------------------------------------------------------
__global__ __launch_bounds__(256) void edge_mfma(
    const short* __restrict__ xbf, const short* __restrict__ btab,
    const int* __restrict__ ei,
    const float* __restrict__ b1, const float* __restrict__ W2,
    const float* __restrict__ b2, float* __restrict__ out,
    int nE, int nTiles) {
  int lane = threadIdx.x & 63;
  int wid  = (blockIdx.x * 256 + threadIdx.x) >> 6;
  int nW   = (gridDim.x * 256) >> 6;
  int m = lane & 15;        // edge-in-tile (A rows) / hidden-in-tile (C cols)
  int q = lane >> 4;        // quad

  if (wid >= nTiles) return;

  bf16x8 B[16];
#pragma unroll
  for (int f = 0; f < 16; ++f)
    B[f] = *(const bf16x8*)(btab + (f * 64 + lane) * 8);

  f32x4 bias[4];
  float w2v[4];
#pragma unroll
  for (int t = 0; t < 4; ++t) {
    float bv = b1[t * 16 + m];
    bias[t] = (f32x4){bv, bv, bv, bv};
    w2v[t] = W2[t * 16 + m];
  }
  float bias2 = b2[0];

  const uint4* xb = (const uint4*)xbf;   // node row = 4 uint4; lane reads row*4+q

  AB mu, mv, mun, mvn;
  {
    int e = wid * 16 + m;
    int ec = e < nE ? e : nE - 1;
    int s = ei[ec], dd = ei[ec + nE];
    mu.u = xb[s * 4 + q];
    mv.u = xb[dd * 4 + q];
  }

  for (int tile = wid; tile < nTiles; ) {
    int nxt = tile + nW;
    if (nxt < nTiles) {                  // prefetch next tile's gathers
      int e = nxt * 16 + m;
      int ec = e < nE ? e : nE - 1;
      int s = ei[ec], dd = ei[ec + nE];
      mun.u = xb[s * 4 + q];
      mvn.u = xb[dd * 4 + q];
    }

    // c = |mu-mv|, p = mu*mv  (dword unpack, v_perm RTZ pack)
    AB ac, ap;
#pragma unroll
    for (int k = 0; k < 4; ++k) {
      unsigned a = (&mu.u.x)[k], b = (&mv.u.x)[k];
      float alo = __uint_as_float(a << 16);
      float ahi = __uint_as_float(a & 0xffff0000u);
      float blo = __uint_as_float(b << 16);
      float bhi = __uint_as_float(b & 0xffff0000u);
      (&ac.u.x)[k] = pack_bf2(fabsf(alo - blo), fabsf(ahi - bhi));
      (&ap.u.x)[k] = pack_bf2(alo * blo, ahi * bhi);
    }

    float part[4];
#pragma unroll
    for (int t = 0; t < 4; ++t) {
      f32x4 acc = bias[t];               // bias as MFMA C-input
      acc = __builtin_amdgcn_mfma_f32_16x16x32_bf16(mu.v, B[t * 4 + 0], acc, 0, 0, 0);
      acc = __builtin_amdgcn_mfma_f32_16x16x32_bf16(mv.v, B[t * 4 + 1], acc, 0, 0, 0);
      acc = __builtin_amdgcn_mfma_f32_16x16x32_bf16(ac.v, B[t * 4 + 2], acc, 0, 0, 0);
      acc = __builtin_amdgcn_mfma_f32_16x16x32_bf16(ap.v, B[t * 4 + 3], acc, 0, 0, 0);
#pragma unroll
      for (int r = 0; r < 4; ++r) {
        float h = fmaxf(acc[r], 0.f);
        part[r] = (t == 0) ? h * w2v[0] : fmaf(h, w2v[t], part[r]);
      }
    }

#pragma unroll
    for (int mask = 1; mask < 16; mask <<= 1)
#pragma unroll
      for (int r = 0; r < 4; ++r)
        part[r] += __shfl_xor(part[r], mask, 64);

    if (m < 4) {
      int ew = tile * 16 + q * 4 + m;
      if (ew < nE) {
        float z = part[m] + bias2;
        float g = 1.f / (1.f + __expf(-z));
        out[ew] = fminf(fmaxf(g, 0.f), 1.f);
      }
    }

    mu = mun; mv = mvn;
    tile = nxt;
  }
}

// ---------------------------------------------------------------------------
// Fallback (ws too small): all-fp32 per edge, no workspace needed.
// ---------------------------------------------------------------------------
__global__ __launch_bounds__(256) void edge_full(
    const float* __restrict__ x, const int* __restrict__ ei,
    const float* __restrict__ W1, const float* __restrict__ b1,
    const float* __restrict__ W2, const float* __restrict__ b2,
    float* __restrict__ out, int nE) {
  int e = blockIdx.x * 256 + threadIdx.x;
  if (e >= nE) return;
  int s = ei[e];
  int d = ei[e + nE];
  const float4* mu4 = (const float4*)(x + (size_t)s * D);
  const float4* mv4 = (const float4*)(x + (size_t)d * D);
  float mu[D], mv[D], c[D], p[D];
#pragma unroll
  for (int qq = 0; qq < D / 4; ++qq) {
    float4 a = mu4[qq];
    float4 b = mv4[qq];
    mu[4*qq+0] = a.x; mv[4*qq+0] = b.x; c[4*qq+0] = fabsf(a.x-b.x); p[4*qq+0] = a.x*b.x;
    mu[4*qq+1] = a.y; mv[4*qq+1] = b.y; c[4*qq+1] = fabsf(a.y-b.y); p[4*qq+1] = a.y*b.y;
    mu[4*qq+2] = a.z; mv[4*qq+2] = b.z; c[4*qq+2] = fabsf(a.z-b.z); p[4*qq+2] = a.z*b.z;
    mu[4*qq+3] = a.w; mv[4*qq+3] = b.w; c[4*qq+3] = fabsf(a.w-b.w); p[4*qq+3] = a.w*b.w;
  }
  float z = b2[0];
  for (int j = 0; j < H; ++j) {
    float a = b1[j];
#pragma unroll
    for (int k = 0; k < D; ++k) {
      a = fmaf(mu[k], W1[k * H + j], a);
      a = fmaf(mv[k], W1[(D + k) * H + j], a);
      a = fmaf(c[k],  W1[(2 * D + k) * H + j], a);
      a = fmaf(p[k],  W1[(3 * D + k) * H + j], a);
    }
    a = fmaxf(a, 0.f);
    z = fmaf(a, W2[j], z);
  }
  float g = 1.f / (1.f + __expf(-z));
  out[e] = fminf(fmaxf(g, 0.f), 1.f);
}

extern "C" void kernel_launch(void* const* d_in, const int* in_sizes, int n_in,
                              void* d_out, int out_size, void* d_ws, size_t ws_size,
                              hipStream_t stream) {
  const float* x  = (const float*)d_in[0];
  const int*   ei = (const int*)d_in[1];
  const float* W1 = (const float*)d_in[2];
  const float* b1 = (const float*)d_in[3];
  const float* W2 = (const float*)d_in[4];
  const float* b2 = (const float*)d_in[5];
  float* out = (float*)d_out;

  int nN = in_sizes[0] / D;      // 100000
  int nE = in_sizes[1] / 2;      // 1600000

  size_t xbf_shorts = (size_t)nN * D;                     // 6.4 MB
  size_t need = (xbf_shorts + 16 * 64 * 8) * sizeof(short);
  if (ws_size >= need) {
    short* xbf  = (short*)d_ws;
    short* btab = xbf + xbf_shorts;
    int n4 = nN * D / 4;
    int nPack = (n4 + 255) / 256;
    int nBt = (16 * 64 * 8 + 255) / 256;
    prep<<<nPack + nBt, 256, 0, stream>>>(x, W1, xbf, btab, n4, nPack);
    int nTiles = (nE + 15) / 16;
    edge_mfma<<<2048, 256, 0, stream>>>(xbf, btab, ei, b1, W2, b2, out, nE, nTiles);
  } else {
    edge_full<<<(nE + 255) / 256, 256, 0, stream>>>(x, ei, W1, b1, W2, b2, out, nE);
  }
}

// Round 5
// 128.469 us; speedup vs baseline: 4.4339x; 1.0130x over previous
//
#include <hip/hip_runtime.h>

#define D 32          // MOTIF_DIM
#define H 64          // HIDDEN

typedef __attribute__((ext_vector_type(8))) short bf16x8;
typedef __attribute__((ext_vector_type(4))) float f32x4;

union AB { uint4 u; bf16x8 v; };

__device__ __forceinline__ short f2bf_s(float f) {   // round-to-nearest-even
  unsigned u = __float_as_uint(f);
  u += 0x7fffu + ((u >> 16) & 1u);
  return (short)(u >> 16);
}

// pack two f32 (lo,hi) into one dword of bf16 [lo | hi<<16], round-to-zero.
__device__ __forceinline__ unsigned pack_bf2(float lo, float hi) {
  return __builtin_amdgcn_perm(__float_as_uint(hi), __float_as_uint(lo), 0x07060302u);
}

// ---------------------------------------------------------------------------
// Fused prep: blocks [0, nPack) convert x fp32 -> bf16 rows (RNE);
// remaining blocks build the W1 B-fragment table (16 frags x 64 lanes x 8 bf16).
// Frag f = t*4+s: lane l elem j = W1[s*32+(l>>4)*8+j][t*16+(l&15)].
// ---------------------------------------------------------------------------
__global__ __launch_bounds__(256) void prep(
    const float* __restrict__ x, const float* __restrict__ W1,
    short* __restrict__ xbf, short* __restrict__ btab, int n4, int nPack) {
  int b = blockIdx.x;
  if (b < nPack) {
    int i = b * 256 + threadIdx.x;
    if (i < n4) {
      float4 v = ((const float4*)x)[i];
      short4 o;
      o.x = f2bf_s(v.x); o.y = f2bf_s(v.y); o.z = f2bf_s(v.z); o.w = f2bf_s(v.w);
      ((short4*)xbf)[i] = o;
    }
  } else {
    int id = (b - nPack) * 256 + threadIdx.x;      // 0..8191
    if (id < 16 * 64 * 8) {
      int j = id & 7;
      int l = (id >> 3) & 63;
      int f = id >> 9;
      int s = f & 3, t = f >> 2;
      int k = s * 32 + (l >> 4) * 8 + j;
      int n = t * 16 + (l & 15);
      btab[id] = f2bf_s(W1[k * H + n]);
    }
  }
}

// ---------------------------------------------------------------------------
// Gather one tile's A-operands: lane reads 16B of bf16 x-row per endpoint.
// Tile/edge indices clamped (tail tiles read valid memory, writes guarded).
// ---------------------------------------------------------------------------
__device__ __forceinline__ void gather_tile(
    const uint4* __restrict__ xb, const int* __restrict__ ei,
    int tile, int m, int q, int nE, int nTiles, uint4& mu, uint4& mv) {
  int tc = tile < nTiles ? tile : nTiles - 1;
  int e  = tc * 16 + m;
  int ec = e < nE ? e : nE - 1;
  int s  = ei[ec];
  int d  = ei[ec + nE];
  mu = xb[s * 4 + q];
  mv = xb[d * 4 + q];
}

__device__ __forceinline__ void compute_tile(
    uint4 muU, uint4 mvU, const bf16x8* __restrict__ B,
    const f32x4* __restrict__ bias, const float* __restrict__ w2v, float bias2,
    int tile, int q, int m, int nE, float* __restrict__ out) {
  AB mu, mv, ac, ap;
  mu.u = muU; mv.u = mvU;
#pragma unroll
  for (int k = 0; k < 4; ++k) {
    unsigned a = (&mu.u.x)[k], b = (&mv.u.x)[k];
    float alo = __uint_as_float(a << 16);
    float ahi = __uint_as_float(a & 0xffff0000u);
    float blo = __uint_as_float(b << 16);
    float bhi = __uint_as_float(b & 0xffff0000u);
    float dlo = alo - blo, dhi = ahi - bhi;
    (&ac.u.x)[k] = pack_bf2(dlo, dhi) & 0x7fff7fffu;   // packed abs
    (&ap.u.x)[k] = pack_bf2(alo * blo, ahi * bhi);
  }

  float part[4];
#pragma unroll
  for (int t = 0; t < 4; ++t) {
    f32x4 acc = bias[t];               // bias as MFMA C-input
    acc = __builtin_amdgcn_mfma_f32_16x16x32_bf16(mu.v, B[t * 4 + 0], acc, 0, 0, 0);
    acc = __builtin_amdgcn_mfma_f32_16x16x32_bf16(mv.v, B[t * 4 + 1], acc, 0, 0, 0);
    acc = __builtin_amdgcn_mfma_f32_16x16x32_bf16(ac.v, B[t * 4 + 2], acc, 0, 0, 0);
    acc = __builtin_amdgcn_mfma_f32_16x16x32_bf16(ap.v, B[t * 4 + 3], acc, 0, 0, 0);
#pragma unroll
    for (int r = 0; r < 4; ++r) {
      float h = fmaxf(acc[r], 0.f);
      part[r] = (t == 0) ? h * w2v[0] : fmaf(h, w2v[t], part[r]);
    }
  }

#pragma unroll
  for (int mask = 1; mask < 16; mask <<= 1)
#pragma unroll
    for (int r = 0; r < 4; ++r)
      part[r] += __shfl_xor(part[r], mask, 64);

  if (m < 4) {
    int ew = tile * 16 + q * 4 + m;    // tile >= nTiles -> ew >= nE -> no write
    if (ew < nE) {
      float z = part[m] + bias2;
      float g = 1.f / (1.f + __expf(-z));
      out[ew] = fminf(fmaxf(g, 0.f), 1.f);
    }
  }
}

// ---------------------------------------------------------------------------
// Main: each wave pipelines TWO independent 16-edge tiles with cross-iteration
// prefetch (8 outstanding gather streams) to hide gather latency.
// ---------------------------------------------------------------------------
__global__ __launch_bounds__(256) void edge_mfma(
    const short* __restrict__ xbf, const short* __restrict__ btab,
    const int* __restrict__ ei,
    const float* __restrict__ b1, const float* __restrict__ W2,
    const float* __restrict__ b2, float* __restrict__ out,
    int nE, int nTiles) {
  int lane = threadIdx.x & 63;
  int wid  = (blockIdx.x * 256 + threadIdx.x) >> 6;
  int nW   = (gridDim.x * 256) >> 6;
  int m = lane & 15;        // edge-in-tile (A rows) / hidden-in-tile (C cols)
  int q = lane >> 4;        // quad

  bf16x8 B[16];
#pragma unroll
  for (int f = 0; f < 16; ++f)
    B[f] = *(const bf16x8*)(btab + (f * 64 + lane) * 8);

  f32x4 bias[4];
  float w2v[4];
#pragma unroll
  for (int t = 0; t < 4; ++t) {
    float bv = b1[t * 16 + m];
    bias[t] = (f32x4){bv, bv, bv, bv};
    w2v[t] = W2[t * 16 + m];
  }
  float bias2 = b2[0];

  const uint4* xb = (const uint4*)xbf;   // node row = 4 uint4; lane reads row*4+q

  int t0 = wid, t1 = wid + nW;
  uint4 mu0, mv0, mu1, mv1;
  gather_tile(xb, ei, t0, m, q, nE, nTiles, mu0, mv0);
  gather_tile(xb, ei, t1, m, q, nE, nTiles, mu1, mv1);

  while (t0 < nTiles) {
    int n0 = t0 + 2 * nW, n1 = t1 + 2 * nW;
    uint4 pmu0, pmv0, pmu1, pmv1;
    gather_tile(xb, ei, n0, m, q, nE, nTiles, pmu0, pmv0);
    gather_tile(xb, ei, n1, m, q, nE, nTiles, pmu1, pmv1);

    compute_tile(mu0, mv0, B, bias, w2v, bias2, t0, q, m, nE, out);
    compute_tile(mu1, mv1, B, bias, w2v, bias2, t1, q, m, nE, out);

    mu0 = pmu0; mv0 = pmv0; mu1 = pmu1; mv1 = pmv1;
    t0 = n0; t1 = n1;
  }
}

// ---------------------------------------------------------------------------
// Fallback (ws too small): all-fp32 per edge, no workspace needed.
// ---------------------------------------------------------------------------
__global__ __launch_bounds__(256) void edge_full(
    const float* __restrict__ x, const int* __restrict__ ei,
    const float* __restrict__ W1, const float* __restrict__ b1,
    const float* __restrict__ W2, const float* __restrict__ b2,
    float* __restrict__ out, int nE) {
  int e = blockIdx.x * 256 + threadIdx.x;
  if (e >= nE) return;
  int s = ei[e];
  int d = ei[e + nE];
  const float4* mu4 = (const float4*)(x + (size_t)s * D);
  const float4* mv4 = (const float4*)(x + (size_t)d * D);
  float mu[D], mv[D], c[D], p[D];
#pragma unroll
  for (int qq = 0; qq < D / 4; ++qq) {
    float4 a = mu4[qq];
    float4 b = mv4[qq];
    mu[4*qq+0] = a.x; mv[4*qq+0] = b.x; c[4*qq+0] = fabsf(a.x-b.x); p[4*qq+0] = a.x*b.x;
    mu[4*qq+1] = a.y; mv[4*qq+1] = b.y; c[4*qq+1] = fabsf(a.y-b.y); p[4*qq+1] = a.y*b.y;
    mu[4*qq+2] = a.z; mv[4*qq+2] = b.z; c[4*qq+2] = fabsf(a.z-b.z); p[4*qq+2] = a.z*b.z;
    mu[4*qq+3] = a.w; mv[4*qq+3] = b.w; c[4*qq+3] = fabsf(a.w-b.w); p[4*qq+3] = a.w*b.w;
  }
  float z = b2[0];
  for (int j = 0; j < H; ++j) {
    float a = b1[j];
#pragma unroll
    for (int k = 0; k < D; ++k) {
      a = fmaf(mu[k], W1[k * H + j], a);
      a = fmaf(mv[k], W1[(D + k) * H + j], a);
      a = fmaf(c[k],  W1[(2 * D + k) * H + j], a);
      a = fmaf(p[k],  W1[(3 * D + k) * H + j], a);
    }
    a = fmaxf(a, 0.f);
    z = fmaf(a, W2[j], z);
  }
  float g = 1.f / (1.f + __expf(-z));
  out[e] = fminf(fmaxf(g, 0.f), 1.f);
}

extern "C" void kernel_launch(void* const* d_in, const int* in_sizes, int n_in,
                              void* d_out, int out_size, void* d_ws, size_t ws_size,
                              hipStream_t stream) {
  const float* x  = (const float*)d_in[0];
  const int*   ei = (const int*)d_in[1];
  const float* W1 = (const float*)d_in[2];
  const float* b1 = (const float*)d_in[3];
  const float* W2 = (const float*)d_in[4];
  const float* b2 = (const float*)d_in[5];
  float* out = (float*)d_out;

  int nN = in_sizes[0] / D;      // 100000
  int nE = in_sizes[1] / 2;      // 1600000

  size_t xbf_shorts = (size_t)nN * D;                     // 6.4 MB
  size_t need = (xbf_shorts + 16 * 64 * 8) * sizeof(short);
  if (ws_size >= need) {
    short* xbf  = (short*)d_ws;
    short* btab = xbf + xbf_shorts;
    int n4 = nN * D / 4;
    int nPack = (n4 + 255) / 256;
    int nBt = (16 * 64 * 8 + 255) / 256;
    prep<<<nPack + nBt, 256, 0, stream>>>(x, W1, xbf, btab, n4, nPack);
    int nTiles = (nE + 15) / 16;
    edge_mfma<<<2048, 256, 0, stream>>>(xbf, btab, ei, b1, W2, b2, out, nE, nTiles);
  } else {
    edge_full<<<(nE + 255) / 256, 256, 0, stream>>>(x, ei, W1, b1, W2, b2, out, nE);
  }
}